// Round 1
// baseline (357.390 us; speedup 1.0000x reference)
//
#include <hip/hip_runtime.h>

constexpr int B_   = 4;
constexpr int NL   = 8192;
constexpr int NH   = 2048;
constexpr int CH   = 256;   // high-level feature channels
constexpr int CL   = 128;   // low-level feature channels
constexpr int CIN  = 384;   // CH + CL
constexpr int COUT = 256;

// ---------------------------------------------------------------------------
// Kernel 1: 3-NN over high points for each low point. d2 computed in f64
// (exact for f32 inputs) so ordering is the true ordering; strict < keeps
// the earlier index on ties (matches jax.lax.top_k stability).
// ---------------------------------------------------------------------------
__global__ __launch_bounds__(256) void knn_kernel(
    const float* __restrict__ xyz_low, const float* __restrict__ xyz_high,
    int* __restrict__ idx0, int* __restrict__ idx1, int* __restrict__ idx2,
    float* __restrict__ w0, float* __restrict__ w1, float* __restrict__ w2)
{
    __shared__ float4 pts[NH];   // 32 KB: x,y,z per high point
    const int b = blockIdx.y;
    const int l = blockIdx.x * 256 + threadIdx.x;

    const float* xh = xyz_high + (size_t)b * NH * 3;
    for (int h = threadIdx.x; h < NH; h += 256) {
        pts[h] = make_float4(xh[h * 3 + 0], xh[h * 3 + 1], xh[h * 3 + 2], 0.0f);
    }
    __syncthreads();

    const float* xl = xyz_low + ((size_t)b * NL + l) * 3;
    const double lx = (double)xl[0], ly = (double)xl[1], lz = (double)xl[2];

    double b0 = 1e300, b1 = 1e300, b2 = 1e300;
    int i0 = 0, i1 = 0, i2 = 0;

    for (int h = 0; h < NH; ++h) {
        float4 p = pts[h];
        double dx = (double)p.x - lx;
        double dy = (double)p.y - ly;
        double dz = (double)p.z - lz;
        double d2 = dx * dx + dy * dy + dz * dz;
        if (d2 < b2) {
            if (d2 < b1) {
                b2 = b1; i2 = i1;
                if (d2 < b0) { b1 = b0; i1 = i0; b0 = d2; i0 = h; }
                else         { b1 = d2; i1 = h; }
            } else {
                b2 = d2; i2 = h;
            }
        }
    }

    float d0 = sqrtf(fmaxf((float)b0, 0.0f));
    float d1 = sqrtf(fmaxf((float)b1, 0.0f));
    float d2f = sqrtf(fmaxf((float)b2, 0.0f));
    float iw0 = 1.0f / fmaxf(d0, 1e-8f);
    float iw1 = 1.0f / fmaxf(d1, 1e-8f);
    float iw2 = 1.0f / fmaxf(d2f, 1e-8f);
    float s = iw0 + iw1 + iw2;

    const size_t g = (size_t)b * NL + l;
    idx0[g] = i0; idx1[g] = i1; idx2[g] = i2;
    w0[g] = iw0 / s; w1[g] = iw1 / s; w2[g] = iw2 / s;
}

// ---------------------------------------------------------------------------
// Kernel 2: inverse-distance interpolation gather -> f_interp (B, CH, NL)
// ---------------------------------------------------------------------------
__global__ __launch_bounds__(256) void interp_kernel(
    const float* __restrict__ feat_high,
    const int* __restrict__ idx0, const int* __restrict__ idx1, const int* __restrict__ idx2,
    const float* __restrict__ w0, const float* __restrict__ w1, const float* __restrict__ w2,
    float* __restrict__ f_interp)
{
    const int b = blockIdx.z;
    const int c = blockIdx.y;
    const int l = blockIdx.x * 256 + threadIdx.x;
    const size_t g = (size_t)b * NL + l;
    const float* row = feat_high + ((size_t)b * CH + c) * NH;
    float v = w0[g] * row[idx0[g]] + w1[g] * row[idx1[g]] + w2[g] * row[idx2[g]];
    f_interp[((size_t)b * CH + c) * NL + l] = v;
}

// ---------------------------------------------------------------------------
// Kernel 3: y[b,o,l] = sum_c W[o,c] * f_cat[b,c,l] + bias[o]
// f_cat rows 0..255 = f_interp, rows 256..383 = feat_low.
// Simple f32 tiled GEMM: 64x64 tile, 256 threads, 4x4 micro-tile, BK=16.
// ---------------------------------------------------------------------------
__global__ __launch_bounds__(256) void gemm_kernel(
    const float* __restrict__ Wm, const float* __restrict__ bias,
    const float* __restrict__ f_interp, const float* __restrict__ feat_low,
    float* __restrict__ y)
{
    __shared__ float Wt[16][64];
    __shared__ float Ft[16][64];

    const int b  = blockIdx.z;
    const int om = blockIdx.y * 64;
    const int ln = blockIdx.x * 64;
    const int t  = threadIdx.x;
    const int tx = t & 15, ty = t >> 4;

    const int wrow = t >> 2;        // 0..63
    const int wc4  = (t & 3) * 4;   // 0,4,8,12
    const int fc   = t >> 4;        // 0..15
    const int fl4  = (t & 15) * 4;  // 0..60

    float acc[4][4] = {};

    for (int k0 = 0; k0 < CIN; k0 += 16) {
        // stage W tile (64 o-rows x 16 c-cols), transposed into Wt[c][o]
        float4 wv = *(const float4*)&Wm[(size_t)(om + wrow) * CIN + k0 + wc4];
        Wt[wc4 + 0][wrow] = wv.x;
        Wt[wc4 + 1][wrow] = wv.y;
        Wt[wc4 + 2][wrow] = wv.z;
        Wt[wc4 + 3][wrow] = wv.w;
        // stage F tile (16 c-rows x 64 l-cols)
        const int c = k0 + fc;
        const float* src = (c < CH)
            ? &f_interp[((size_t)b * CH + c) * NL + ln + fl4]
            : &feat_low[((size_t)b * CL + (c - CH)) * NL + ln + fl4];
        *(float4*)&Ft[fc][fl4] = *(const float4*)src;
        __syncthreads();

        #pragma unroll
        for (int kk = 0; kk < 16; ++kk) {
            float4 av = *(const float4*)&Wt[kk][ty * 4];
            float4 bv = *(const float4*)&Ft[kk][tx * 4];
            const float a0 = av.x, a1 = av.y, a2 = av.z, a3 = av.w;
            const float c0 = bv.x, c1 = bv.y, c2 = bv.z, c3 = bv.w;
            acc[0][0] = fmaf(a0, c0, acc[0][0]); acc[0][1] = fmaf(a0, c1, acc[0][1]);
            acc[0][2] = fmaf(a0, c2, acc[0][2]); acc[0][3] = fmaf(a0, c3, acc[0][3]);
            acc[1][0] = fmaf(a1, c0, acc[1][0]); acc[1][1] = fmaf(a1, c1, acc[1][1]);
            acc[1][2] = fmaf(a1, c2, acc[1][2]); acc[1][3] = fmaf(a1, c3, acc[1][3]);
            acc[2][0] = fmaf(a2, c0, acc[2][0]); acc[2][1] = fmaf(a2, c1, acc[2][1]);
            acc[2][2] = fmaf(a2, c2, acc[2][2]); acc[2][3] = fmaf(a2, c3, acc[2][3]);
            acc[3][0] = fmaf(a3, c0, acc[3][0]); acc[3][1] = fmaf(a3, c1, acc[3][1]);
            acc[3][2] = fmaf(a3, c2, acc[3][2]); acc[3][3] = fmaf(a3, c3, acc[3][3]);
        }
        __syncthreads();
    }

    #pragma unroll
    for (int i = 0; i < 4; ++i) {
        const int o = om + ty * 4 + i;
        const float bi = bias[o];
        float4 out;
        out.x = acc[i][0] + bi;
        out.y = acc[i][1] + bi;
        out.z = acc[i][2] + bi;
        out.w = acc[i][3] + bi;
        *(float4*)&y[((size_t)b * COUT + o) * NL + ln + tx * 4] = out;
    }
}

// ---------------------------------------------------------------------------
// Kernel 4: per-channel batch stats over (B, NL) -> mean, rstd
// ---------------------------------------------------------------------------
__global__ __launch_bounds__(256) void bn_stats_kernel(
    const float* __restrict__ y, float* __restrict__ mean, float* __restrict__ rstd)
{
    const int o = blockIdx.x;
    float s = 0.0f, sq = 0.0f;
    for (int b = 0; b < B_; ++b) {
        const float* row = y + ((size_t)b * COUT + o) * NL;
        for (int l = threadIdx.x * 4; l < NL; l += 1024) {
            float4 v = *(const float4*)&row[l];
            s  += v.x + v.y + v.z + v.w;
            sq += v.x * v.x + v.y * v.y + v.z * v.z + v.w * v.w;
        }
    }
    #pragma unroll
    for (int off = 32; off > 0; off >>= 1) {
        s  += __shfl_down(s, off);
        sq += __shfl_down(sq, off);
    }
    __shared__ float ls[4], lq[4];
    const int wid = threadIdx.x >> 6, lane = threadIdx.x & 63;
    if (lane == 0) { ls[wid] = s; lq[wid] = sq; }
    __syncthreads();
    if (threadIdx.x == 0) {
        s  = ls[0] + ls[1] + ls[2] + ls[3];
        sq = lq[0] + lq[1] + lq[2] + lq[3];
        const float n = (float)(B_ * NL);
        const float m = s / n;
        const float var = sq / n - m * m;
        mean[o] = m;
        rstd[o] = rsqrtf(var + 1e-5f);
    }
}

// ---------------------------------------------------------------------------
// Kernel 5: in-place BN apply + ReLU on y (= d_out)
// ---------------------------------------------------------------------------
__global__ __launch_bounds__(256) void bn_apply_kernel(
    float* __restrict__ y,
    const float* __restrict__ mean, const float* __restrict__ rstd,
    const float* __restrict__ gamma, const float* __restrict__ beta)
{
    const size_t e4 = (size_t)blockIdx.x * 256 + threadIdx.x;  // float4 index
    const int oc = (int)((e4 / (NL / 4)) % COUT);
    float4 v = ((const float4*)y)[e4];
    const float m = mean[oc], r = rstd[oc], g = gamma[oc], be = beta[oc];
    v.x = fmaxf(fmaf(g, (v.x - m) * r, be), 0.0f);
    v.y = fmaxf(fmaf(g, (v.y - m) * r, be), 0.0f);
    v.z = fmaxf(fmaf(g, (v.z - m) * r, be), 0.0f);
    v.w = fmaxf(fmaf(g, (v.w - m) * r, be), 0.0f);
    ((float4*)y)[e4] = v;
}

// ---------------------------------------------------------------------------
extern "C" void kernel_launch(void* const* d_in, const int* in_sizes, int n_in,
                              void* d_out, int out_size, void* d_ws, size_t ws_size,
                              hipStream_t stream)
{
    const float* xyz_low   = (const float*)d_in[0];
    const float* xyz_high  = (const float*)d_in[1];
    const float* feat_low  = (const float*)d_in[2];
    const float* feat_high = (const float*)d_in[3];
    const float* Wm        = (const float*)d_in[4];
    const float* bias      = (const float*)d_in[5];
    const float* gamma     = (const float*)d_in[6];
    const float* beta      = (const float*)d_in[7];
    float* y = (float*)d_out;

    const size_t npts = (size_t)B_ * NL;
    int*   idx0 = (int*)d_ws;
    int*   idx1 = idx0 + npts;
    int*   idx2 = idx1 + npts;
    float* w0   = (float*)(idx2 + npts);
    float* w1   = w0 + npts;
    float* w2   = w1 + npts;
    float* mean = w2 + npts;
    float* rstd = mean + COUT;
    float* f_interp = rstd + COUT;   // (B, CH, NL) floats, 16B-aligned

    dim3 knn_grid(NL / 256, B_);
    knn_kernel<<<knn_grid, 256, 0, stream>>>(xyz_low, xyz_high,
                                             idx0, idx1, idx2, w0, w1, w2);

    dim3 it_grid(NL / 256, CH, B_);
    interp_kernel<<<it_grid, 256, 0, stream>>>(feat_high, idx0, idx1, idx2,
                                               w0, w1, w2, f_interp);

    dim3 gm_grid(NL / 64, COUT / 64, B_);
    gemm_kernel<<<gm_grid, 256, 0, stream>>>(Wm, bias, f_interp, feat_low, y);

    bn_stats_kernel<<<COUT, 256, 0, stream>>>(y, mean, rstd);

    bn_apply_kernel<<<(B_ * COUT * NL / 4) / 256, 256, 0, stream>>>(
        y, mean, rstd, gamma, beta);
}

// Round 2
// 150.593 us; speedup vs baseline: 2.3732x; 2.3732x over previous
//
#include <hip/hip_runtime.h>

constexpr int B_   = 4;
constexpr int NL   = 8192;
constexpr int NH   = 2048;
constexpr int CH   = 256;
constexpr int CL   = 128;
constexpr int CIN  = 384;
constexpr int COUT = 256;

typedef _Float16 f16;
typedef _Float16 f16x8 __attribute__((ext_vector_type(8)));
typedef float    f32x4 __attribute__((ext_vector_type(4)));

// ---------------------------------------------------------------------------
// Kernel 1: 3-NN. 4 threads per low point, each scans 512 high points (f64
// exact distances, strict < keeps earliest index on ties), LDS merge of the
// 4x top-3 candidate lists in slice order (preserves tie stability).
// ---------------------------------------------------------------------------
__global__ __launch_bounds__(256) void knn_kernel(
    const float* __restrict__ xyz_low, const float* __restrict__ xyz_high,
    int* __restrict__ idx0, int* __restrict__ idx1, int* __restrict__ idx2,
    float* __restrict__ w0, float* __restrict__ w1, float* __restrict__ w2)
{
    __shared__ float4 pts[NH];        // 32 KB
    __shared__ double md[64 * 12];    // 6 KB
    __shared__ int    mi_[64 * 12];   // 3 KB

    const int b   = blockIdx.y;
    const int tid = threadIdx.x;
    const int p   = tid >> 2;         // point within block (0..63)
    const int s   = tid & 3;          // NH slice (0..3)
    const int l   = blockIdx.x * 64 + p;

    const float* xh = xyz_high + (size_t)b * NH * 3;
    for (int h = tid; h < NH; h += 256)
        pts[h] = make_float4(xh[h * 3], xh[h * 3 + 1], xh[h * 3 + 2], 0.0f);
    __syncthreads();

    const float* xl = xyz_low + ((size_t)b * NL + l) * 3;
    const double lx = (double)xl[0], ly = (double)xl[1], lz = (double)xl[2];

    double b0 = 1e300, b1 = 1e300, b2 = 1e300;
    int i0 = 0, i1 = 0, i2 = 0;
    const int h0 = s * 512;
    for (int h = h0; h < h0 + 512; ++h) {
        float4 pt = pts[h];
        double dx = (double)pt.x - lx;
        double dy = (double)pt.y - ly;
        double dz = (double)pt.z - lz;
        double d2 = dx * dx + dy * dy + dz * dz;
        if (d2 < b2) {
            if (d2 < b1) {
                b2 = b1; i2 = i1;
                if (d2 < b0) { b1 = b0; i1 = i0; b0 = d2; i0 = h; }
                else         { b1 = d2; i1 = h; }
            } else { b2 = d2; i2 = h; }
        }
    }
    const int base = p * 12 + s * 3;
    md[base] = b0; mi_[base] = i0;
    md[base + 1] = b1; mi_[base + 1] = i1;
    md[base + 2] = b2; mi_[base + 2] = i2;
    __syncthreads();

    if (tid < 64) {
        double c0 = 1e300, c1 = 1e300, c2 = 1e300;
        int j0 = 0, j1 = 0, j2 = 0;
        #pragma unroll
        for (int q = 0; q < 12; ++q) {
            double d = md[tid * 12 + q];
            int   ii = mi_[tid * 12 + q];
            if (d < c2) {
                if (d < c1) {
                    c2 = c1; j2 = j1;
                    if (d < c0) { c1 = c0; j1 = j0; c0 = d; j0 = ii; }
                    else        { c1 = d; j1 = ii; }
                } else { c2 = d; j2 = ii; }
            }
        }
        float d0 = sqrtf(fmaxf((float)c0, 0.0f));
        float d1 = sqrtf(fmaxf((float)c1, 0.0f));
        float d2f = sqrtf(fmaxf((float)c2, 0.0f));
        float iw0 = 1.0f / fmaxf(d0, 1e-8f);
        float iw1 = 1.0f / fmaxf(d1, 1e-8f);
        float iw2 = 1.0f / fmaxf(d2f, 1e-8f);
        float sum = iw0 + iw1 + iw2;
        const size_t g = (size_t)b * NL + blockIdx.x * 64 + tid;
        idx0[g] = j0; idx1[g] = j1; idx2[g] = j2;
        w0[g] = iw0 / sum; w1[g] = iw1 / sum; w2[g] = iw2 / sum;
    }
}

// ---------------------------------------------------------------------------
// Kernel 2a: transpose feat_high (B,CH,NH) f32 -> fhT (B,NH,CH) fp16
// ---------------------------------------------------------------------------
__global__ __launch_bounds__(256) void transpose_fh(
    const float* __restrict__ fh, f16* __restrict__ fhT)
{
    __shared__ float t[32][33];
    const int b = blockIdx.z, c0 = blockIdx.y * 32, h0 = blockIdx.x * 32;
    const int tx = threadIdx.x & 31, ty = threadIdx.x >> 5;
    #pragma unroll
    for (int p = 0; p < 4; ++p)
        t[ty + p * 8][tx] = fh[((size_t)b * CH + c0 + ty + p * 8) * NH + h0 + tx];
    __syncthreads();
    #pragma unroll
    for (int p = 0; p < 4; ++p)
        fhT[((size_t)b * NH + h0 + ty + p * 8) * CH + c0 + tx] = (f16)t[tx][ty + p * 8];
}

// ---------------------------------------------------------------------------
// Kernel 2b: transpose feat_low (B,CL,NL) f32 -> f_catT[b][l][256+cl] fp16
// ---------------------------------------------------------------------------
__global__ __launch_bounds__(256) void transpose_fl(
    const float* __restrict__ fl, f16* __restrict__ fcat)
{
    __shared__ float t[32][33];
    const int b = blockIdx.z, c0 = blockIdx.y * 32, l0 = blockIdx.x * 32;
    const int tx = threadIdx.x & 31, ty = threadIdx.x >> 5;
    #pragma unroll
    for (int p = 0; p < 4; ++p)
        t[ty + p * 8][tx] = fl[((size_t)b * CL + c0 + ty + p * 8) * NL + l0 + tx];
    __syncthreads();
    #pragma unroll
    for (int p = 0; p < 4; ++p)
        fcat[((size_t)b * NL + l0 + ty + p * 8) * CIN + CH + c0 + tx] = (f16)t[tx][ty + p * 8];
}

// ---------------------------------------------------------------------------
// Kernel 2c: W (COUT,CIN) f32 -> fp16
// ---------------------------------------------------------------------------
__global__ __launch_bounds__(256) void convert_w(
    const float* __restrict__ W, f16* __restrict__ Wh)
{
    const int i = blockIdx.x * 256 + threadIdx.x;
    Wh[i] = (f16)W[i];
}

// ---------------------------------------------------------------------------
// Kernel 3: interpolation gather -> f_catT[b][l][0..255] fp16.
// thread = channel c (coalesced row reads of fhT and row writes of f_catT).
// ---------------------------------------------------------------------------
__global__ __launch_bounds__(256) void interp_kernel(
    const f16* __restrict__ fhT,
    const int* __restrict__ idx0, const int* __restrict__ idx1, const int* __restrict__ idx2,
    const float* __restrict__ w0, const float* __restrict__ w1, const float* __restrict__ w2,
    f16* __restrict__ fcat)
{
    const int b = blockIdx.y;
    const int l0 = blockIdx.x * 32;
    const int c = threadIdx.x;
    const f16* base = fhT + (size_t)b * NH * CH;
    #pragma unroll 4
    for (int i = 0; i < 32; ++i) {
        const size_t g = (size_t)b * NL + l0 + i;
        float v = w0[g] * (float)base[(size_t)idx0[g] * CH + c]
                + w1[g] * (float)base[(size_t)idx1[g] * CH + c]
                + w2[g] * (float)base[(size_t)idx2[g] * CH + c];
        fcat[g * CIN + c] = (f16)v;
    }
}

// ---------------------------------------------------------------------------
// Kernel 4: fp16 MFMA GEMM. y[b,o,l] = sum_k Wh[o,k] * fcatT[b,l,k] + bias[o]
// Block: 256 threads = 4 waves; tile = 256(o) x 64(l); BK=32, 12 K-steps.
// Wave w owns o-range [w*64, w*64+64). D[m=o][n=l] stores straight into
// d_out's (B,COUT,NL) layout, 64B-coalesced.
// ---------------------------------------------------------------------------
__global__ __launch_bounds__(256) void gemm_kernel(
    const f16* __restrict__ Wh, const float* __restrict__ bias,
    const f16* __restrict__ fcat, float* __restrict__ y)
{
    __shared__ f16 Wt[256 * 40];   // [o][k], pad to 40 f16 (80 B) rows
    __shared__ f16 As[64 * 40];    // [l][k]

    const int b   = blockIdx.y;
    const int l0  = blockIdx.x * 64;
    const int tid = threadIdx.x;
    const int lane = tid & 63;
    const int w   = tid >> 6;

    f32x4 acc[4][4] = {};

    const int sl = tid >> 2;          // 0..63
    const int sk = (tid & 3) * 8;     // 0,8,16,24
    const f16* fbase = fcat + ((size_t)b * NL + l0 + sl) * CIN + sk;

    for (int kt = 0; kt < 12; ++kt) {
        const int k0 = kt * 32;
        *(f16x8*)&As[sl * 40 + sk] = *(const f16x8*)(fbase + k0);
        #pragma unroll
        for (int p = 0; p < 4; ++p) {
            const int o = sl + p * 64;
            *(f16x8*)&Wt[o * 40 + sk] = *(const f16x8*)&Wh[o * CIN + k0 + sk];
        }
        __syncthreads();

        const int kb = (lane >> 4) * 8;
        const int r  = lane & 15;
        f16x8 a[4], bb[4];
        #pragma unroll
        for (int mi = 0; mi < 4; ++mi)
            a[mi] = *(const f16x8*)&Wt[(w * 64 + mi * 16 + r) * 40 + kb];
        #pragma unroll
        for (int ni = 0; ni < 4; ++ni)
            bb[ni] = *(const f16x8*)&As[(ni * 16 + r) * 40 + kb];
        #pragma unroll
        for (int mi = 0; mi < 4; ++mi)
            #pragma unroll
            for (int ni = 0; ni < 4; ++ni)
                acc[mi][ni] = __builtin_amdgcn_mfma_f32_16x16x32_f16(
                    a[mi], bb[ni], acc[mi][ni], 0, 0, 0);
        __syncthreads();
    }

    const int r4 = (lane >> 4) * 4;
    const int cl = lane & 15;
    #pragma unroll
    for (int mi = 0; mi < 4; ++mi) {
        #pragma unroll
        for (int j = 0; j < 4; ++j) {
            const int o = w * 64 + mi * 16 + r4 + j;
            const float bi = bias[o];
            float* dst = &y[((size_t)b * COUT + o) * NL + l0 + cl];
            #pragma unroll
            for (int ni = 0; ni < 4; ++ni)
                dst[ni * 16] = acc[mi][ni][j] + bi;
        }
    }
}

// ---------------------------------------------------------------------------
// Kernel 5: per-channel batch stats over (B, NL) -> mean, rstd
// ---------------------------------------------------------------------------
__global__ __launch_bounds__(256) void bn_stats_kernel(
    const float* __restrict__ y, float* __restrict__ mean, float* __restrict__ rstd)
{
    const int o = blockIdx.x;
    float s = 0.0f, sq = 0.0f;
    for (int b = 0; b < B_; ++b) {
        const float* row = y + ((size_t)b * COUT + o) * NL;
        for (int l = threadIdx.x * 4; l < NL; l += 1024) {
            float4 v = *(const float4*)&row[l];
            s  += v.x + v.y + v.z + v.w;
            sq += v.x * v.x + v.y * v.y + v.z * v.z + v.w * v.w;
        }
    }
    #pragma unroll
    for (int off = 32; off > 0; off >>= 1) {
        s  += __shfl_down(s, off);
        sq += __shfl_down(sq, off);
    }
    __shared__ float ls[4], lq[4];
    const int wid = threadIdx.x >> 6, lane = threadIdx.x & 63;
    if (lane == 0) { ls[wid] = s; lq[wid] = sq; }
    __syncthreads();
    if (threadIdx.x == 0) {
        s  = ls[0] + ls[1] + ls[2] + ls[3];
        sq = lq[0] + lq[1] + lq[2] + lq[3];
        const float n = (float)(B_ * NL);
        const float m = s / n;
        const float var = sq / n - m * m;
        mean[o] = m;
        rstd[o] = rsqrtf(var + 1e-5f);
    }
}

// ---------------------------------------------------------------------------
// Kernel 6: in-place BN apply + ReLU on y (= d_out)
// ---------------------------------------------------------------------------
__global__ __launch_bounds__(256) void bn_apply_kernel(
    float* __restrict__ y,
    const float* __restrict__ mean, const float* __restrict__ rstd,
    const float* __restrict__ gamma, const float* __restrict__ beta)
{
    const size_t e4 = (size_t)blockIdx.x * 256 + threadIdx.x;
    const int oc = (int)((e4 / (NL / 4)) % COUT);
    float4 v = ((const float4*)y)[e4];
    const float m = mean[oc], r = rstd[oc], g = gamma[oc], be = beta[oc];
    v.x = fmaxf(fmaf(g, (v.x - m) * r, be), 0.0f);
    v.y = fmaxf(fmaf(g, (v.y - m) * r, be), 0.0f);
    v.z = fmaxf(fmaf(g, (v.z - m) * r, be), 0.0f);
    v.w = fmaxf(fmaf(g, (v.w - m) * r, be), 0.0f);
    ((float4*)y)[e4] = v;
}

// ---------------------------------------------------------------------------
extern "C" void kernel_launch(void* const* d_in, const int* in_sizes, int n_in,
                              void* d_out, int out_size, void* d_ws, size_t ws_size,
                              hipStream_t stream)
{
    const float* xyz_low   = (const float*)d_in[0];
    const float* xyz_high  = (const float*)d_in[1];
    const float* feat_low  = (const float*)d_in[2];
    const float* feat_high = (const float*)d_in[3];
    const float* Wm        = (const float*)d_in[4];
    const float* bias      = (const float*)d_in[5];
    const float* gamma     = (const float*)d_in[6];
    const float* beta      = (const float*)d_in[7];
    float* y = (float*)d_out;

    const size_t npts = (size_t)B_ * NL;
    char* ws = (char*)d_ws;
    int*   idx0 = (int*)ws;
    int*   idx1 = idx0 + npts;
    int*   idx2 = idx1 + npts;
    float* w0   = (float*)(idx2 + npts);
    float* w1   = w0 + npts;
    float* w2   = w1 + npts;
    float* mean = w2 + npts;
    float* rstd = mean + COUT;
    f16*   Wh   = (f16*)(rstd + COUT);                    // 98304 f16
    f16*   fhT  = Wh + (size_t)COUT * CIN;                // B*NH*CH f16
    f16*   fcat = fhT + (size_t)B_ * NH * CH;             // B*NL*CIN f16

    transpose_fh<<<dim3(NH / 32, CH / 32, B_), 256, 0, stream>>>(feat_high, fhT);
    convert_w<<<(COUT * CIN) / 256, 256, 0, stream>>>(Wm, Wh);
    knn_kernel<<<dim3(NL / 64, B_), 256, 0, stream>>>(xyz_low, xyz_high,
                                                      idx0, idx1, idx2, w0, w1, w2);
    transpose_fl<<<dim3(NL / 32, CL / 32, B_), 256, 0, stream>>>(feat_low, fcat);
    interp_kernel<<<dim3(NL / 32, B_), 256, 0, stream>>>(fhT, idx0, idx1, idx2,
                                                         w0, w1, w2, fcat);
    gemm_kernel<<<dim3(NL / 64, B_), 256, 0, stream>>>(Wh, bias, fcat, y);
    bn_stats_kernel<<<COUT, 256, 0, stream>>>(y, mean, rstd);
    bn_apply_kernel<<<(B_ * COUT * NL / 4) / 256, 256, 0, stream>>>(
        y, mean, rstd, gamma, beta);
}

// Round 3
// 94.004 us; speedup vs baseline: 3.8019x; 1.6020x over previous
//
#include <hip/hip_runtime.h>

constexpr int B_   = 4;
constexpr int NL   = 8192;
constexpr int NH   = 2048;
constexpr int CH   = 256;
constexpr int CL   = 128;
constexpr int CIN  = 384;
constexpr int COUT = 256;

typedef _Float16 f16;
typedef _Float16 f16x8 __attribute__((ext_vector_type(8)));
typedef float    f32x4 __attribute__((ext_vector_type(4)));

// ---------------------------------------------------------------------------
// Kernel 1: 3-NN. 1024 threads = 16 waves; wave w scans NH-slice
// [w*128, w*128+128) for 64 low points (lane = point). pts[h] read is
// wave-uniform -> LDS broadcast, no bank conflicts. d2 uses the reference's
// expanded f32 form (sl + sh - 2*dot) so near-tie ordering mimics the ref.
// Merge in slice order with strict < preserves earliest-index tie rule.
// ---------------------------------------------------------------------------
__global__ __launch_bounds__(1024, 8) void knn_kernel(
    const float* __restrict__ xyz_low, const float* __restrict__ xyz_high,
    int* __restrict__ idx0, int* __restrict__ idx1, int* __restrict__ idx2,
    float* __restrict__ w0, float* __restrict__ w1, float* __restrict__ w2)
{
    __shared__ float4 pts[NH];          // 32 KB: x,y,z,|p|^2
    __shared__ float  md[64 * 49];      // stride 49 (coprime 32) -> no conflicts
    __shared__ int    mi_[64 * 49];

    const int b   = blockIdx.y;
    const int tid = threadIdx.x;
    const int w   = tid >> 6;           // slice 0..15
    const int p   = tid & 63;           // point 0..63
    const int l   = blockIdx.x * 64 + p;

    const float* xh = xyz_high + (size_t)b * NH * 3;
    for (int h = tid; h < NH; h += 1024) {
        float x = xh[h * 3], y = xh[h * 3 + 1], z = xh[h * 3 + 2];
        pts[h] = make_float4(x, y, z, x * x + y * y + z * z);
    }
    __syncthreads();

    const float* xl = xyz_low + ((size_t)b * NL + l) * 3;
    const float lx = xl[0], ly = xl[1], lz = xl[2];
    const float sl = lx * lx + ly * ly + lz * lz;

    float b0 = 1e30f, b1 = 1e30f, b2 = 1e30f;
    int i0 = 0, i1 = 0, i2 = 0;
    const int h0 = w * 128;
    #pragma unroll 4
    for (int h = h0; h < h0 + 128; ++h) {
        float4 pt = pts[h];
        float dot = fmaf(lx, pt.x, fmaf(ly, pt.y, lz * pt.z));
        float d2 = fmaf(-2.0f, dot, sl + pt.w);
        if (d2 < b2) {
            if (d2 < b1) {
                b2 = b1; i2 = i1;
                if (d2 < b0) { b1 = b0; i1 = i0; b0 = d2; i0 = h; }
                else         { b1 = d2; i1 = h; }
            } else { b2 = d2; i2 = h; }
        }
    }
    const int base = p * 49 + w * 3;
    md[base] = b0;     mi_[base] = i0;
    md[base + 1] = b1; mi_[base + 1] = i1;
    md[base + 2] = b2; mi_[base + 2] = i2;
    __syncthreads();

    if (tid < 64) {
        float c0 = 1e30f, c1 = 1e30f, c2 = 1e30f;
        int j0 = 0, j1 = 0, j2 = 0;
        #pragma unroll
        for (int q = 0; q < 48; ++q) {
            float d = md[tid * 49 + q];
            int  ii = mi_[tid * 49 + q];
            if (d < c2) {
                if (d < c1) {
                    c2 = c1; j2 = j1;
                    if (d < c0) { c1 = c0; j1 = j0; c0 = d; j0 = ii; }
                    else        { c1 = d; j1 = ii; }
                } else { c2 = d; j2 = ii; }
            }
        }
        float d0 = sqrtf(fmaxf(c0, 0.0f));
        float d1 = sqrtf(fmaxf(c1, 0.0f));
        float d2f = sqrtf(fmaxf(c2, 0.0f));
        float iw0 = 1.0f / fmaxf(d0, 1e-8f);
        float iw1 = 1.0f / fmaxf(d1, 1e-8f);
        float iw2 = 1.0f / fmaxf(d2f, 1e-8f);
        float sum = iw0 + iw1 + iw2;
        const size_t g = (size_t)b * NL + blockIdx.x * 64 + tid;
        idx0[g] = j0; idx1[g] = j1; idx2[g] = j2;
        w0[g] = iw0 / sum; w1[g] = iw1 / sum; w2[g] = iw2 / sum;
    }
}

// ---------------------------------------------------------------------------
// Kernel 2a: transpose feat_high (B,CH,NH) f32 -> fhT (B,NH,CH) fp16
// ---------------------------------------------------------------------------
__global__ __launch_bounds__(256) void transpose_fh(
    const float* __restrict__ fh, f16* __restrict__ fhT)
{
    __shared__ float t[32][33];
    const int b = blockIdx.z, c0 = blockIdx.y * 32, h0 = blockIdx.x * 32;
    const int tx = threadIdx.x & 31, ty = threadIdx.x >> 5;
    #pragma unroll
    for (int p = 0; p < 4; ++p)
        t[ty + p * 8][tx] = fh[((size_t)b * CH + c0 + ty + p * 8) * NH + h0 + tx];
    __syncthreads();
    #pragma unroll
    for (int p = 0; p < 4; ++p)
        fhT[((size_t)b * NH + h0 + ty + p * 8) * CH + c0 + tx] = (f16)t[tx][ty + p * 8];
}

// ---------------------------------------------------------------------------
// Kernel 2b: transpose feat_low (B,CL,NL) f32 -> f_catT[b][l][256+cl] fp16
// ---------------------------------------------------------------------------
__global__ __launch_bounds__(256) void transpose_fl(
    const float* __restrict__ fl, f16* __restrict__ fcat)
{
    __shared__ float t[32][33];
    const int b = blockIdx.z, c0 = blockIdx.y * 32, l0 = blockIdx.x * 32;
    const int tx = threadIdx.x & 31, ty = threadIdx.x >> 5;
    #pragma unroll
    for (int p = 0; p < 4; ++p)
        t[ty + p * 8][tx] = fl[((size_t)b * CL + c0 + ty + p * 8) * NL + l0 + tx];
    __syncthreads();
    #pragma unroll
    for (int p = 0; p < 4; ++p)
        fcat[((size_t)b * NL + l0 + ty + p * 8) * CIN + CH + c0 + tx] = (f16)t[tx][ty + p * 8];
}

__global__ __launch_bounds__(256) void convert_w(
    const float* __restrict__ W, f16* __restrict__ Wh)
{
    const int i = blockIdx.x * 256 + threadIdx.x;
    Wh[i] = (f16)W[i];
}

// ---------------------------------------------------------------------------
// Kernel 3: interpolation gather -> f_catT[b][l][0..255] fp16
// ---------------------------------------------------------------------------
__global__ __launch_bounds__(256) void interp_kernel(
    const f16* __restrict__ fhT,
    const int* __restrict__ idx0, const int* __restrict__ idx1, const int* __restrict__ idx2,
    const float* __restrict__ w0, const float* __restrict__ w1, const float* __restrict__ w2,
    f16* __restrict__ fcat)
{
    const int b = blockIdx.y;
    const int l0 = blockIdx.x * 32;
    const int c = threadIdx.x;
    const f16* base = fhT + (size_t)b * NH * CH;
    #pragma unroll 4
    for (int i = 0; i < 32; ++i) {
        const size_t g = (size_t)b * NL + l0 + i;
        float v = w0[g] * (float)base[(size_t)idx0[g] * CH + c]
                + w1[g] * (float)base[(size_t)idx1[g] * CH + c]
                + w2[g] * (float)base[(size_t)idx2[g] * CH + c];
        fcat[g * CIN + c] = (f16)v;
    }
}

// ---------------------------------------------------------------------------
// Kernel 4: fp16 MFMA GEMM + per-block BN partial sums.
// Block: 256 thr = 4 waves; tile 256(o) x 64(l); BK=32. Epilogue reduces
// (sum, sumsq) over the block's 64 l-columns per channel -> ps/psq[o][bidx].
// ---------------------------------------------------------------------------
__global__ __launch_bounds__(256) void gemm_kernel(
    const f16* __restrict__ Wh, const float* __restrict__ bias,
    const f16* __restrict__ fcat, float* __restrict__ y,
    float* __restrict__ ps, float* __restrict__ psq)
{
    __shared__ f16 Wt[256 * 40];
    __shared__ f16 As[64 * 40];

    const int b   = blockIdx.y;
    const int l0  = blockIdx.x * 64;
    const int bidx = blockIdx.y * 128 + blockIdx.x;   // 0..511
    const int tid = threadIdx.x;
    const int lane = tid & 63;
    const int w   = tid >> 6;

    f32x4 acc[4][4] = {};

    const int sl = tid >> 2;
    const int sk = (tid & 3) * 8;
    const f16* fbase = fcat + ((size_t)b * NL + l0 + sl) * CIN + sk;

    for (int kt = 0; kt < 12; ++kt) {
        const int k0 = kt * 32;
        *(f16x8*)&As[sl * 40 + sk] = *(const f16x8*)(fbase + k0);
        #pragma unroll
        for (int p = 0; p < 4; ++p) {
            const int o = sl + p * 64;
            *(f16x8*)&Wt[o * 40 + sk] = *(const f16x8*)&Wh[o * CIN + k0 + sk];
        }
        __syncthreads();

        const int kb = (lane >> 4) * 8;
        const int r  = lane & 15;
        f16x8 a[4], bb[4];
        #pragma unroll
        for (int mi = 0; mi < 4; ++mi)
            a[mi] = *(const f16x8*)&Wt[(w * 64 + mi * 16 + r) * 40 + kb];
        #pragma unroll
        for (int ni = 0; ni < 4; ++ni)
            bb[ni] = *(const f16x8*)&As[(ni * 16 + r) * 40 + kb];
        #pragma unroll
        for (int mi = 0; mi < 4; ++mi)
            #pragma unroll
            for (int ni = 0; ni < 4; ++ni)
                acc[mi][ni] = __builtin_amdgcn_mfma_f32_16x16x32_f16(
                    a[mi], bb[ni], acc[mi][ni], 0, 0, 0);
        __syncthreads();
    }

    const int r4 = (lane >> 4) * 4;
    const int cl = lane & 15;
    #pragma unroll
    for (int mi = 0; mi < 4; ++mi) {
        #pragma unroll
        for (int j = 0; j < 4; ++j) {
            const int o = w * 64 + mi * 16 + r4 + j;
            const float bi = bias[o];
            float* dst = &y[((size_t)b * COUT + o) * NL + l0 + cl];
            float s = 0.0f, sq = 0.0f;
            #pragma unroll
            for (int ni = 0; ni < 4; ++ni) {
                float v = acc[mi][ni][j] + bi;
                dst[ni * 16] = v;
                s += v; sq += v * v;
            }
            #pragma unroll
            for (int m = 1; m < 16; m <<= 1) {
                s  += __shfl_xor(s, m);
                sq += __shfl_xor(sq, m);
            }
            if (cl == 0) {
                ps [o * 512 + bidx] = s;
                psq[o * 512 + bidx] = sq;
            }
        }
    }
}

// ---------------------------------------------------------------------------
// Kernel 5: deterministic tree-reduce of the 512 per-block partials.
// ---------------------------------------------------------------------------
__global__ __launch_bounds__(256) void bn_stats_kernel(
    const float* __restrict__ ps, const float* __restrict__ psq,
    float* __restrict__ mean, float* __restrict__ rstd)
{
    const int o = blockIdx.x;
    const int t = threadIdx.x;
    float s = ps[o * 512 + t] + ps[o * 512 + 256 + t];
    float q = psq[o * 512 + t] + psq[o * 512 + 256 + t];
    #pragma unroll
    for (int m = 32; m > 0; m >>= 1) {
        s += __shfl_down(s, m);
        q += __shfl_down(q, m);
    }
    __shared__ float ls[4], lq[4];
    const int wid = t >> 6, lane = t & 63;
    if (lane == 0) { ls[wid] = s; lq[wid] = q; }
    __syncthreads();
    if (t == 0) {
        s = ls[0] + ls[1] + ls[2] + ls[3];
        q = lq[0] + lq[1] + lq[2] + lq[3];
        const float n = (float)(B_ * NL);
        const float m = s / n;
        const float var = q / n - m * m;
        mean[o] = m;
        rstd[o] = rsqrtf(var + 1e-5f);
    }
}

// ---------------------------------------------------------------------------
// Kernel 6: in-place BN apply + ReLU on y (= d_out)
// ---------------------------------------------------------------------------
__global__ __launch_bounds__(256) void bn_apply_kernel(
    float* __restrict__ y,
    const float* __restrict__ mean, const float* __restrict__ rstd,
    const float* __restrict__ gamma, const float* __restrict__ beta)
{
    const size_t e4 = (size_t)blockIdx.x * 256 + threadIdx.x;
    const int oc = (int)((e4 / (NL / 4)) % COUT);
    float4 v = ((const float4*)y)[e4];
    const float m = mean[oc], r = rstd[oc], g = gamma[oc], be = beta[oc];
    v.x = fmaxf(fmaf(g, (v.x - m) * r, be), 0.0f);
    v.y = fmaxf(fmaf(g, (v.y - m) * r, be), 0.0f);
    v.z = fmaxf(fmaf(g, (v.z - m) * r, be), 0.0f);
    v.w = fmaxf(fmaf(g, (v.w - m) * r, be), 0.0f);
    ((float4*)y)[e4] = v;
}

// ---------------------------------------------------------------------------
extern "C" void kernel_launch(void* const* d_in, const int* in_sizes, int n_in,
                              void* d_out, int out_size, void* d_ws, size_t ws_size,
                              hipStream_t stream)
{
    const float* xyz_low   = (const float*)d_in[0];
    const float* xyz_high  = (const float*)d_in[1];
    const float* feat_low  = (const float*)d_in[2];
    const float* feat_high = (const float*)d_in[3];
    const float* Wm        = (const float*)d_in[4];
    const float* bias      = (const float*)d_in[5];
    const float* gamma     = (const float*)d_in[6];
    const float* beta      = (const float*)d_in[7];
    float* y = (float*)d_out;

    const size_t npts = (size_t)B_ * NL;
    char* ws = (char*)d_ws;
    int*   idx0 = (int*)ws;
    int*   idx1 = idx0 + npts;
    int*   idx2 = idx1 + npts;
    float* w0   = (float*)(idx2 + npts);
    float* w1   = w0 + npts;
    float* w2   = w1 + npts;
    float* mean = w2 + npts;
    float* rstd = mean + COUT;
    f16*   Wh   = (f16*)(rstd + COUT);                    // COUT*CIN f16
    f16*   fhT  = Wh + (size_t)COUT * CIN;                // B*NH*CH f16 (4MB)
    f16*   fcat = fhT + (size_t)B_ * NH * CH;             // B*NL*CIN f16
    // ps/psq overlap fhT: fhT is dead once interp_kernel completes (pre-gemm)
    float* ps   = (float*)fhT;                            // 256*512 f32
    float* psq  = ps + (size_t)COUT * 512;                // 256*512 f32

    transpose_fh<<<dim3(NH / 32, CH / 32, B_), 256, 0, stream>>>(feat_high, fhT);
    convert_w<<<(COUT * CIN) / 256, 256, 0, stream>>>(Wm, Wh);
    knn_kernel<<<dim3(NL / 64, B_), 1024, 0, stream>>>(xyz_low, xyz_high,
                                                       idx0, idx1, idx2, w0, w1, w2);
    transpose_fl<<<dim3(NL / 32, CL / 32, B_), 256, 0, stream>>>(feat_low, fcat);
    interp_kernel<<<dim3(NL / 32, B_), 256, 0, stream>>>(fhT, idx0, idx1, idx2,
                                                         w0, w1, w2, fcat);
    gemm_kernel<<<dim3(NL / 64, B_), 256, 0, stream>>>(Wh, bias, fcat, y, ps, psq);
    bn_stats_kernel<<<COUT, 256, 0, stream>>>(ps, psq, mean, rstd);
    bn_apply_kernel<<<(B_ * COUT * NL / 4) / 256, 256, 0, stream>>>(
        y, mean, rstd, gamma, beta);
}

// Round 4
// 91.394 us; speedup vs baseline: 3.9104x; 1.0286x over previous
//
#include <hip/hip_runtime.h>

constexpr int B_   = 4;
constexpr int NL   = 8192;
constexpr int NH   = 2048;
constexpr int CH   = 256;
constexpr int CL   = 128;
constexpr int CIN  = 384;
constexpr int COUT = 256;

typedef _Float16 f16;
typedef _Float16 f16x8 __attribute__((ext_vector_type(8)));
typedef float    f32x4 __attribute__((ext_vector_type(4)));

#define INS3(d, i, B0, B1, B2, I0, I1, I2)                                  \
    if ((d) < (B2)) {                                                       \
        if ((d) < (B1)) {                                                   \
            B2 = B1; I2 = I1;                                               \
            if ((d) < (B0)) { B1 = B0; I1 = I0; B0 = (d); I0 = (i); }       \
            else            { B1 = (d); I1 = (i); }                         \
        } else { B2 = (d); I2 = (i); }                                      \
    }

// ---------------------------------------------------------------------------
// Kernel 1: 3-NN. 1024 thr = 16 waves; 128 low points per block, 2 per lane.
// Wave w scans NH-slice [w*128, w*128+128): pts[h] is wave-uniform (LDS
// broadcast, conflict-free) and serves both points. d2 uses the reference's
// expanded f32 form (sl + sh - 2*dot). Two-stage parallel merge (12+12
// serial steps); strict < everywhere keeps earliest index on ties.
// ---------------------------------------------------------------------------
__global__ __launch_bounds__(1024, 4) void knn_kernel(
    const float* __restrict__ xyz_low, const float* __restrict__ xyz_high,
    int* __restrict__ idx0, int* __restrict__ idx1, int* __restrict__ idx2,
    float* __restrict__ w0, float* __restrict__ w1, float* __restrict__ w2)
{
    __shared__ float4 pts[NH];                  // 32 KB (reused by md2/mi2)
    __shared__ float  md[128 * 49];             // 25 KB, stride 49 (odd)
    __shared__ unsigned short mi[128 * 49];     // 12.5 KB
    float*          md2 = reinterpret_cast<float*>(pts);            // 6.7 KB
    unsigned short* mi2 = reinterpret_cast<unsigned short*>(pts + 512); // 3.3 KB

    const int b   = blockIdx.y;
    const int tid = threadIdx.x;
    const int w   = tid >> 6;                   // wave 0..15
    const int p   = tid & 63;                   // lane
    const int lA  = blockIdx.x * 128 + p;
    const int lB  = lA + 64;

    const float* xh = xyz_high + (size_t)b * NH * 3;
    for (int h = tid; h < NH; h += 1024) {
        float x = xh[h * 3], y = xh[h * 3 + 1], z = xh[h * 3 + 2];
        pts[h] = make_float4(x, y, z, x * x + y * y + z * z);
    }
    __syncthreads();

    const float* xlA = xyz_low + ((size_t)b * NL + lA) * 3;
    const float* xlB = xyz_low + ((size_t)b * NL + lB) * 3;
    const float lxA = xlA[0], lyA = xlA[1], lzA = xlA[2];
    const float lxB = xlB[0], lyB = xlB[1], lzB = xlB[2];
    const float slA = lxA * lxA + lyA * lyA + lzA * lzA;
    const float slB = lxB * lxB + lyB * lyB + lzB * lzB;

    float a0 = 1e30f, a1 = 1e30f, a2 = 1e30f;
    float c0 = 1e30f, c1 = 1e30f, c2 = 1e30f;
    int ia0 = 0, ia1 = 0, ia2 = 0, ic0 = 0, ic1 = 0, ic2 = 0;

    const int h0 = w * 128;
    #pragma unroll 2
    for (int h = h0; h < h0 + 128; ++h) {
        float4 pt = pts[h];
        float dA = fmaf(-2.0f, fmaf(lxA, pt.x, fmaf(lyA, pt.y, lzA * pt.z)),
                        slA + pt.w);
        float dB = fmaf(-2.0f, fmaf(lxB, pt.x, fmaf(lyB, pt.y, lzB * pt.z)),
                        slB + pt.w);
        INS3(dA, h, a0, a1, a2, ia0, ia1, ia2);
        INS3(dB, h, c0, c1, c2, ic0, ic1, ic2);
    }
    const int baseA = p * 49 + w * 3;
    const int baseB = (p + 64) * 49 + w * 3;
    md[baseA] = a0;     mi[baseA] = (unsigned short)ia0;
    md[baseA + 1] = a1; mi[baseA + 1] = (unsigned short)ia1;
    md[baseA + 2] = a2; mi[baseA + 2] = (unsigned short)ia2;
    md[baseB] = c0;     mi[baseB] = (unsigned short)ic0;
    md[baseB + 1] = c1; mi[baseB + 1] = (unsigned short)ic1;
    md[baseB + 2] = c2; mi[baseB + 2] = (unsigned short)ic2;
    __syncthreads();

    if (tid < 512) {                            // stage 1: 4 thr/point
        const int pr = tid >> 2, q = tid & 3;
        float e0 = 1e30f, e1 = 1e30f, e2 = 1e30f;
        int j0 = 0, j1 = 0, j2 = 0;
        const int src = pr * 49 + q * 12;
        #pragma unroll
        for (int t2 = 0; t2 < 12; ++t2) {
            float d = md[src + t2];
            int  ii = mi[src + t2];
            INS3(d, ii, e0, e1, e2, j0, j1, j2);
        }
        const int dst = pr * 13 + q * 3;
        md2[dst] = e0;     mi2[dst] = (unsigned short)j0;
        md2[dst + 1] = e1; mi2[dst + 1] = (unsigned short)j1;
        md2[dst + 2] = e2; mi2[dst + 2] = (unsigned short)j2;
    }
    __syncthreads();

    if (tid < 128) {                            // stage 2: final 12-way
        float e0 = 1e30f, e1 = 1e30f, e2 = 1e30f;
        int j0 = 0, j1 = 0, j2 = 0;
        #pragma unroll
        for (int t2 = 0; t2 < 12; ++t2) {
            float d = md2[tid * 13 + t2];
            int  ii = mi2[tid * 13 + t2];
            INS3(d, ii, e0, e1, e2, j0, j1, j2);
        }
        float d0 = sqrtf(fmaxf(e0, 0.0f));
        float d1 = sqrtf(fmaxf(e1, 0.0f));
        float d2f = sqrtf(fmaxf(e2, 0.0f));
        float iw0 = 1.0f / fmaxf(d0, 1e-8f);
        float iw1 = 1.0f / fmaxf(d1, 1e-8f);
        float iw2 = 1.0f / fmaxf(d2f, 1e-8f);
        float sum = iw0 + iw1 + iw2;
        const size_t g = (size_t)b * NL + blockIdx.x * 128 + tid;
        idx0[g] = j0; idx1[g] = j1; idx2[g] = j2;
        w0[g] = iw0 / sum; w1[g] = iw1 / sum; w2[g] = iw2 / sum;
    }
}

// ---------------------------------------------------------------------------
// Kernel 2: fused prep — role by blockIdx.x:
//   [0,2048)    transpose feat_high (B,CH,NH) f32 -> fhT (B,NH,CH) fp16
//   [2048,6144) transpose feat_low  (B,CL,NL) f32 -> flT (B,NL,CL) fp16
//   [6144,6528) convert W f32 -> fp16
// ---------------------------------------------------------------------------
__global__ __launch_bounds__(256) void prep_kernel(
    const float* __restrict__ fh, const float* __restrict__ fl,
    const float* __restrict__ W,
    f16* __restrict__ fhT, f16* __restrict__ flT, f16* __restrict__ Wh)
{
    __shared__ float t[32][33];
    const int bid = blockIdx.x;
    const int tx = threadIdx.x & 31, ty = threadIdx.x >> 5;

    if (bid < 2048) {                 // t_fh: 512 tiles/batch (64 h x 8 c)
        const int b = bid >> 9, tt = bid & 511;
        const int h0 = (tt & 63) * 32, c0 = (tt >> 6) * 32;
        #pragma unroll
        for (int pp = 0; pp < 4; ++pp)
            t[ty + pp * 8][tx] = fh[((size_t)b * CH + c0 + ty + pp * 8) * NH + h0 + tx];
        __syncthreads();
        #pragma unroll
        for (int pp = 0; pp < 4; ++pp)
            fhT[((size_t)b * NH + h0 + ty + pp * 8) * CH + c0 + tx] =
                (f16)t[tx][ty + pp * 8];
    } else if (bid < 6144) {          // t_fl: 1024 tiles/batch (256 l x 4 c)
        const int id = bid - 2048;
        const int b = id >> 10, tt = id & 1023;
        const int l0 = (tt & 255) * 32, c0 = (tt >> 8) * 32;
        #pragma unroll
        for (int pp = 0; pp < 4; ++pp)
            t[ty + pp * 8][tx] = fl[((size_t)b * CL + c0 + ty + pp * 8) * NL + l0 + tx];
        __syncthreads();
        #pragma unroll
        for (int pp = 0; pp < 4; ++pp)
            flT[((size_t)b * NL + l0 + ty + pp * 8) * CL + c0 + tx] =
                (f16)t[tx][ty + pp * 8];
    } else {                          // conv_w
        const int i = (bid - 6144) * 256 + threadIdx.x;
        Wh[i] = (f16)W[i];
    }
}

// ---------------------------------------------------------------------------
// Kernel 3: fused interp + fp16 MFMA GEMM + BN partial sums.
// Block: 256 thr = 4 waves; tile 256(o) x 64(l). Prologue gathers the
// interpolated A-tile (k<256) and feat_low (k>=256) into LDS As[64][392].
// K-loop: BK=32, Wt staged per step. Epilogue: f32 acc + bias -> partial
// (sum,sumsq) per channel, y stored fp16 via LDS-coalesced pass.
// ---------------------------------------------------------------------------
__global__ __launch_bounds__(256, 2) void gemm_kernel(
    const f16* __restrict__ Wh, const float* __restrict__ bias,
    const f16* __restrict__ fhT, const f16* __restrict__ flT,
    const int* __restrict__ idx0, const int* __restrict__ idx1,
    const int* __restrict__ idx2,
    const float* __restrict__ w0, const float* __restrict__ w1,
    const float* __restrict__ w2,
    f16* __restrict__ yh, float* __restrict__ ps, float* __restrict__ psq)
{
    __shared__ f16 As[64 * 392];   // 50.2 KB  [l][k], stride 392 (49x16B, odd)
    __shared__ f16 Wt[256 * 40];   // 20.5 KB  [o][k], stride 40 (5x16B, odd)

    const int b    = blockIdx.y;
    const int l0   = blockIdx.x * 64;
    const int bidx = blockIdx.y * 128 + blockIdx.x;      // 0..511
    const int tid  = threadIdx.x;
    const int lane = tid & 63;
    const int w    = tid >> 6;

    // ---- prologue: interp gather (k<256) + feat_low copy (k>=256) ----
    {
        const int p = tid >> 2;            // point 0..63
        const int q = tid & 3;             // channel quarter
        const size_t g = (size_t)b * NL + l0 + p;
        const int j0 = idx0[g], j1 = idx1[g], j2 = idx2[g];
        const float u0 = w0[g], u1 = w1[g], u2 = w2[g];
        const f16* r0 = fhT + ((size_t)b * NH + j0) * CH + q * 64;
        const f16* r1 = fhT + ((size_t)b * NH + j1) * CH + q * 64;
        const f16* r2 = fhT + ((size_t)b * NH + j2) * CH + q * 64;
        #pragma unroll
        for (int j = 0; j < 8; ++j) {
            f16x8 v0 = *(const f16x8*)(r0 + j * 8);
            f16x8 v1 = *(const f16x8*)(r1 + j * 8);
            f16x8 v2 = *(const f16x8*)(r2 + j * 8);
            f16x8 o;
            #pragma unroll
            for (int e = 0; e < 8; ++e)
                o[e] = (f16)(u0 * (float)v0[e] + u1 * (float)v1[e]
                             + u2 * (float)v2[e]);
            *(f16x8*)&As[p * 392 + q * 64 + j * 8] = o;
        }
        const f16* rl = flT + ((size_t)b * NL + l0 + p) * CL + q * 32;
        #pragma unroll
        for (int j = 0; j < 4; ++j)
            *(f16x8*)&As[p * 392 + 256 + q * 32 + j * 8] =
                *(const f16x8*)(rl + j * 8);
    }

    f32x4 acc[4][4] = {};
    const int kb = (lane >> 4) * 8;
    const int r  = lane & 15;

    for (int kt = 0; kt < 12; ++kt) {
        const int k0 = kt * 32;
        #pragma unroll
        for (int pp = 0; pp < 4; ++pp) {
            const int o = (tid >> 2) + pp * 64;
            *(f16x8*)&Wt[o * 40 + (tid & 3) * 8] =
                *(const f16x8*)&Wh[o * CIN + k0 + (tid & 3) * 8];
        }
        __syncthreads();   // As (first iter) + Wt ready; prev MFMA done

        f16x8 a[4], bb[4];
        #pragma unroll
        for (int mi = 0; mi < 4; ++mi)
            a[mi] = *(const f16x8*)&Wt[(w * 64 + mi * 16 + r) * 40 + kb];
        #pragma unroll
        for (int ni = 0; ni < 4; ++ni)
            bb[ni] = *(const f16x8*)&As[(ni * 16 + r) * 392 + k0 + kb];
        #pragma unroll
        for (int mi = 0; mi < 4; ++mi)
            #pragma unroll
            for (int ni = 0; ni < 4; ++ni)
                acc[mi][ni] = __builtin_amdgcn_mfma_f32_16x16x32_f16(
                    a[mi], bb[ni], acc[mi][ni], 0, 0, 0);
        __syncthreads();   // Wt consumed (and As, before Ys aliasing)
    }

    // ---- epilogue: bias, BN partials, fp16 store via LDS (alias As) ----
    f16* Ys = As;                      // [256][72] fp16 = 36.9 KB
    const int r4 = (lane >> 4) * 4;
    const int cl = lane & 15;
    #pragma unroll
    for (int mi = 0; mi < 4; ++mi) {
        #pragma unroll
        for (int j = 0; j < 4; ++j) {
            const int o = w * 64 + mi * 16 + r4 + j;
            const float bi = bias[o];
            float s = 0.0f, sq = 0.0f;
            #pragma unroll
            for (int ni = 0; ni < 4; ++ni) {
                float v = acc[mi][ni][j] + bi;
                Ys[o * 72 + cl + ni * 16] = (f16)v;
                s += v; sq += v * v;
            }
            #pragma unroll
            for (int m = 1; m < 16; m <<= 1) {
                s  += __shfl_xor(s, m);
                sq += __shfl_xor(sq, m);
            }
            if (cl == 0) {
                ps [o * 512 + bidx] = s;
                psq[o * 512 + bidx] = sq;
            }
        }
    }
    __syncthreads();
    {
        const int q = tid & 3;
        #pragma unroll
        for (int rep = 0; rep < 4; ++rep) {
            const int o = rep * 64 + (tid >> 2);
            f16* dst = yh + ((size_t)b * COUT + o) * NL + l0 + q * 16;
            *(f16x8*)(dst)     = *(const f16x8*)&Ys[o * 72 + q * 16];
            *(f16x8*)(dst + 8) = *(const f16x8*)&Ys[o * 72 + q * 16 + 8];
        }
    }
}

// ---------------------------------------------------------------------------
// Kernel 4: deterministic tree-reduce of the 512 per-block partials.
// ---------------------------------------------------------------------------
__global__ __launch_bounds__(256) void bn_stats_kernel(
    const float* __restrict__ ps, const float* __restrict__ psq,
    float* __restrict__ mean, float* __restrict__ rstd)
{
    const int o = blockIdx.x;
    const int t = threadIdx.x;
    float s = ps[o * 512 + t] + ps[o * 512 + 256 + t];
    float q = psq[o * 512 + t] + psq[o * 512 + 256 + t];
    #pragma unroll
    for (int m = 32; m > 0; m >>= 1) {
        s += __shfl_down(s, m);
        q += __shfl_down(q, m);
    }
    __shared__ float ls[4], lq[4];
    const int wid = t >> 6, lane = t & 63;
    if (lane == 0) { ls[wid] = s; lq[wid] = q; }
    __syncthreads();
    if (t == 0) {
        s = ls[0] + ls[1] + ls[2] + ls[3];
        q = lq[0] + lq[1] + lq[2] + lq[3];
        const float n = (float)(B_ * NL);
        const float m = s / n;
        const float var = q / n - m * m;
        mean[o] = m;
        rstd[o] = rsqrtf(var + 1e-5f);
    }
}

// ---------------------------------------------------------------------------
// Kernel 5: BN apply + ReLU: read yh fp16, write f32 d_out.
// ---------------------------------------------------------------------------
__global__ __launch_bounds__(256) void bn_apply_kernel(
    const f16* __restrict__ yh, float* __restrict__ y,
    const float* __restrict__ mean, const float* __restrict__ rstd,
    const float* __restrict__ gamma, const float* __restrict__ beta)
{
    const size_t e8 = (size_t)blockIdx.x * 256 + threadIdx.x;  // f16x8 group
    const int oc = (int)((e8 >> 10) & (COUT - 1));             // NL/8 = 1024
    f16x8 v = ((const f16x8*)yh)[e8];
    const float m = mean[oc], rs = rstd[oc], g = gamma[oc], be = beta[oc];
    float4 o1, o2;
    o1.x = fmaxf(fmaf(g, ((float)v[0] - m) * rs, be), 0.0f);
    o1.y = fmaxf(fmaf(g, ((float)v[1] - m) * rs, be), 0.0f);
    o1.z = fmaxf(fmaf(g, ((float)v[2] - m) * rs, be), 0.0f);
    o1.w = fmaxf(fmaf(g, ((float)v[3] - m) * rs, be), 0.0f);
    o2.x = fmaxf(fmaf(g, ((float)v[4] - m) * rs, be), 0.0f);
    o2.y = fmaxf(fmaf(g, ((float)v[5] - m) * rs, be), 0.0f);
    o2.z = fmaxf(fmaf(g, ((float)v[6] - m) * rs, be), 0.0f);
    o2.w = fmaxf(fmaf(g, ((float)v[7] - m) * rs, be), 0.0f);
    ((float4*)y)[e8 * 2]     = o1;
    ((float4*)y)[e8 * 2 + 1] = o2;
}

// ---------------------------------------------------------------------------
extern "C" void kernel_launch(void* const* d_in, const int* in_sizes, int n_in,
                              void* d_out, int out_size, void* d_ws, size_t ws_size,
                              hipStream_t stream)
{
    const float* xyz_low   = (const float*)d_in[0];
    const float* xyz_high  = (const float*)d_in[1];
    const float* feat_low  = (const float*)d_in[2];
    const float* feat_high = (const float*)d_in[3];
    const float* Wm        = (const float*)d_in[4];
    const float* bias      = (const float*)d_in[5];
    const float* gamma     = (const float*)d_in[6];
    const float* beta      = (const float*)d_in[7];
    float* y = (float*)d_out;

    const size_t npts = (size_t)B_ * NL;
    int*   idx0 = (int*)d_ws;
    int*   idx1 = idx0 + npts;
    int*   idx2 = idx1 + npts;
    float* w0   = (float*)(idx2 + npts);
    float* w1   = w0 + npts;
    float* w2   = w1 + npts;
    float* mean = w2 + npts;
    float* rstd = mean + COUT;
    float* ps   = rstd + COUT;                       // 256*512 f32
    float* psq  = ps + (size_t)COUT * 512;           // 256*512 f32
    f16*   Wh   = (f16*)(psq + (size_t)COUT * 512);  // COUT*CIN
    f16*   fhT  = Wh + (size_t)COUT * CIN;           // B*NH*CH (4.2 MB)
    f16*   flT  = fhT + (size_t)B_ * NH * CH;        // B*NL*CL (8.4 MB)
    f16*   yh   = flT + (size_t)B_ * NL * CL;        // B*COUT*NL (16.8 MB)

    knn_kernel<<<dim3(NL / 128, B_), 1024, 0, stream>>>(
        xyz_low, xyz_high, idx0, idx1, idx2, w0, w1, w2);
    prep_kernel<<<6528, 256, 0, stream>>>(feat_high, feat_low, Wm, fhT, flT, Wh);
    gemm_kernel<<<dim3(NL / 64, B_), 256, 0, stream>>>(
        Wh, bias, fhT, flT, idx0, idx1, idx2, w0, w1, w2, yh, ps, psq);
    bn_stats_kernel<<<COUT, 256, 0, stream>>>(ps, psq, mean, rstd);
    bn_apply_kernel<<<(int)(npts * COUT / 8 / 256), 256, 0, stream>>>(
        yh, y, mean, rstd, gamma, beta);
}